// Round 3
// baseline (551.601 us; speedup 1.0000x reference)
//
#include <hip/hip_runtime.h>

#define TPB 256
#define SPB 4
#define NSAMP 8192

#if __has_builtin(__builtin_amdgcn_rcpf)
#define RCPF(x) __builtin_amdgcn_rcpf(x)
#else
#define RCPF(x) (1.0f/(x))
#endif
#if __has_builtin(__builtin_amdgcn_rsqf)
#define RSQF(x) __builtin_amdgcn_rsqf(x)
#else
#define RSQF(x) rsqrtf(x)
#endif

// ---- s_dyn float offsets ----
#define O_CENT   0      // [2][8][64] hop-1 centers (url=0,user=1)
#define O_CRN    1024   // [16] reciprocal clamped norms
#define O_ORI    1040   // [64] ori_user
#define O_ORN    1104   // [1]  (+3 pad)
#define O_URLEMB 1108   // [64]
#define O_JOB    1172   // [2][8][64] combined hop-2 outputs (atomic accum)
#define O_H1     2196   // [2][8][64] relu(W2 linear) (atomic accum, b2-preinit)
#define O_PIDX   3220   // [208] ints: 4-bit packed ids
#define O_W      3428   // [256] hop-2 weights (l2u,l2l,u2u,u2l)
#define O_GA1    3684   // [2][64] hop-1 attention outputs
#define O_PART   3812   // [4][64] W1 partials
#define O_W1H    4068   // [16] hop-1 weights (u1u 0..7, u1l 8..15)
#define O_CIDX   4084   // [12] ints (user 7, url 5)
#define DYN_SZ   4096

__device__ __forceinline__ float sx(float v, int m) { return __shfl_xor(v, m, 64); }

// 16-lane sum reduce entirely in the VALU pipe via DPP.
// ctrl must be a compile-time constant for __builtin_amdgcn_update_dpp.
template <int CTRL>
__device__ __forceinline__ float dpp_add(float v) {
  return v + __int_as_float(__builtin_amdgcn_update_dpp(
      0, __float_as_int(v), CTRL, 0xf, 0xf, true));
}
__device__ __forceinline__ float red16(float v) {
  v = dpp_add<0xB1>(v);   // quad_perm(1,0,3,2)  = xor1
  v = dpp_add<0x4E>(v);   // quad_perm(2,3,0,1)  = xor2
  v = dpp_add<0x141>(v);  // row_half_mirror     -> combines quad pairs
  v = dpp_add<0x140>(v);  // row_mirror          -> combines across quads
  return v;
}

__global__ __launch_bounds__(TPB, 4)
void gcn_fused(const int* __restrict__ g_user_f, const int* __restrict__ g_url_f,
               const int* __restrict__ g_u1u_f, const float* __restrict__ g_u1u_w,
               const int* __restrict__ g_u1l_f, const float* __restrict__ g_u1l_w,
               const int* __restrict__ g_u2u_f, const float* __restrict__ g_u2u_w,
               const int* __restrict__ g_u2l_f, const float* __restrict__ g_u2l_w,
               const int* __restrict__ g_l2u_f, const float* __restrict__ g_l2u_w,
               const int* __restrict__ g_l2l_f, const float* __restrict__ g_l2l_w,
               const float* __restrict__ g_utab, const float* __restrict__ g_ltab,
               const float* __restrict__ g_W2, const float* __restrict__ g_b2,
               const float* __restrict__ g_W1, const float* __restrict__ g_b1,
               const float* __restrict__ g_Wo, const float* __restrict__ g_bo,
               float* __restrict__ g_out)
{
  __shared__ __align__(16) float s_lut[5376];  // user rows [0,3136), url rows [3136,5376), stride 64
  __shared__ __align__(16) float s_dyn[DYN_SZ];

  const int tid  = threadIdx.x;
  const int wv   = tid >> 6;        // wave 0..3
  const int lane = tid & 63;
  const int g    = (tid >> 4) & 3;  // 16-lane group in wave
  const int l    = tid & 15;        // owns dims l*4..l*4+3

  float* s_ulut = s_lut;
  float* s_llut = s_lut + 49*64;
  int*   s_pidx = (int*)&s_dyn[O_PIDX];
  int*   s_cidx = (int*)&s_dyn[O_CIDX];
  float* s_h1   = &s_dyn[O_H1];

  // ---------- once per block: W2^T/W1^T columns into registers (s_lut as scratch) ----------
  float w2r[32], w1r[32];
#define LOAD_WT(Wg, wr)                                              \
  for (int half = 0; half < 2; ++half) {                             \
    for (int i = tid; i < 4096; i += TPB) {                          \
      const int r = i >> 7, j = i & 127;                             \
      s_lut[r*132 + j] = Wg[(half*32 + r)*128 + j];                  \
    }                                                                \
    __syncthreads();                                                 \
    if ((lane >> 5) == half) {                                       \
      const int lr = lane & 31;                                      \
      _Pragma("unroll")                                              \
      for (int jj = 0; jj < 32; ++jj)                                \
        wr[jj] = s_lut[lr*132 + wv*32 + jj];                         \
    }                                                                \
    __syncthreads();                                                 \
  }
  LOAD_WT(g_W2, w2r)
  LOAD_WT(g_W1, w1r)
#undef LOAD_WT

  // ---------- once per block: stage embedding LUTs (49+35 live rows only) ----------
  {
    constexpr int uoff[7] = {0,11577,11588,11599,11610,11621,11642};
    #pragma unroll
    for (int c = 0; c < 7; ++c)
      for (int i = tid; i < 448; i += TPB)
        s_ulut[c*448 + i] = g_utab[(uoff[c] + (i >> 6))*64 + (i & 63)];
    constexpr int loff[5] = {0,4733,4754,4761,4772};
    #pragma unroll
    for (int c = 0; c < 5; ++c)
      for (int i = tid; i < 448; i += TPB)
        s_llut[c*448 + i] = g_ltab[(loff[c] + (i >> 6))*64 + (i & 63)];
  }

  const float b2v = g_b2[lane];
  const float b1v = g_b1[lane];
  float wo0 = 0.f, wo1 = 0.f, wo2 = 0.f, wo3 = 0.f;
  if (wv == 0) { wo0 = g_Wo[lane]; wo1 = g_Wo[64+lane]; wo2 = g_Wo[128+lane]; wo3 = g_Wo[192+lane]; }
  const float bo0 = g_bo[0], bo1 = g_bo[1];

  // per-wave hop-2 job: jb0=url_2_user, jb1=url_2_url, jb2=user_2_user, jb3=user_2_url
  const int  jb      = wv;
  const bool F7      = (jb == 0 || jb == 2);
  const int  F3      = F7 ? 7 : 5;
  const float* lut3  = F7 ? s_ulut : s_llut;
  const int  nibbase = (jb == 0) ? 768 : (jb == 1) ? 1216 : (jb == 2) ? 0 : 448;
  const int  b3      = jb >> 1;   // 0=url-branch centers, 1=user-branch

  #pragma unroll 1
  for (int s = 0; s < SPB; ++s) {
    const int n = blockIdx.x * SPB + s;
    __syncthreads();   // prev-sample readers done before restaging

    // ---------- stage 1: pack ids (4-bit), stage weights, init JOB/H1 ----------
    if (tid < 192) {           // hop-2: 1536 ids -> 192 words [u2u,u2l,l2u,l2l]
      const int w = tid;
      const int* ptr; int rel;
      if (w < 56)       { ptr = g_u2u_f + n*448; rel = w; }
      else if (w < 96)  { ptr = g_u2l_f + n*320; rel = w - 56; }
      else if (w < 152) { ptr = g_l2u_f + n*448; rel = w - 96; }
      else              { ptr = g_l2l_f + n*320; rel = w - 152; }
      const int4 a = *(const int4*)(ptr + rel*8);
      const int4 b = *(const int4*)(ptr + rel*8 + 4);
      s_pidx[w] = (a.x&7) | ((a.y&7)<<4) | ((a.z&7)<<8) | ((a.w&7)<<12)
                | ((b.x&7)<<16) | ((b.y&7)<<20) | ((b.z&7)<<24) | ((b.w&7)<<28);
    } else if (tid < 204) {    // u1u (7 words) + u1l (5 words)
      const int w = tid - 192;
      const int* ptr; int rel;
      if (w < 7) { ptr = g_u1u_f + n*56; rel = w; } else { ptr = g_u1l_f + n*40; rel = w - 7; }
      const int4 a = *(const int4*)(ptr + rel*8);
      const int4 b = *(const int4*)(ptr + rel*8 + 4);
      s_pidx[192 + w] = (a.x&7) | ((a.y&7)<<4) | ((a.z&7)<<8) | ((a.w&7)<<12)
                      | ((b.x&7)<<16) | ((b.y&7)<<20) | ((b.z&7)<<24) | ((b.w&7)<<28);
    } else if (tid < 216) {    // center ids, unpacked
      const int t = tid - 204;
      s_cidx[t] = (t < 7) ? g_user_f[n*7 + t] : g_url_f[n*5 + (t - 7)];
    } else if (tid < 232) {    // hop-1 weights
      const int t = tid - 216;
      s_dyn[O_W1H + t] = (t < 8) ? g_u1u_w[n*8 + t] : g_u1l_w[n*8 + (t - 8)];
    }
    if (tid < 64) {            // hop-2 weights, float4
      const float* wp = (tid < 16) ? g_l2u_w : (tid < 32) ? g_l2l_w
                       : (tid < 48) ? g_u2u_w : g_u2l_w;
      *(float4*)&s_dyn[O_W + (tid >> 4)*64 + (tid & 15)*4] =
          *(const float4*)&wp[n*64 + (tid & 15)*4];
    }
    *(float4*)&s_dyn[O_JOB + tid*4] = make_float4(0.f, 0.f, 0.f, 0.f);
    #pragma unroll
    for (int r = 0; r < 4; ++r) s_h1[(wv*4 + r)*64 + lane] = b2v;   // b2 pre-init
    __syncthreads();

    // ---------- stage 2: hop-1 centers + ori_user + url_embed ----------
    {
      const int gg = tid >> 4;          // 0..7 url centers, 8..15 user centers (wave-uniform F)
      const bool isUser = gg >= 8;
      const int k = gg & 7;
      const float* lut = isUser ? s_ulut : s_llut;
      const int nb = isUser ? (1536 + k*7) : (1592 + k*5);
      const int wq = nb >> 3;
      unsigned long long u =
          ((unsigned long long)(unsigned)s_pidx[wq + 1] << 32) | (unsigned)s_pidx[wq];
      u >>= ((nb & 7) << 2);
      float4 e = make_float4(0.f,0.f,0.f,0.f);
      if (isUser) {
        #pragma unroll
        for (int c = 0; c < 7; ++c) {
          const int id = (int)(u >> (c*4)) & 7;
          const float4 t = *(const float4*)&lut[((c*7 + id) << 6) + (l << 2)];
          e.x += t.x; e.y += t.y; e.z += t.z; e.w += t.w;
        }
      } else {
        #pragma unroll
        for (int c = 0; c < 5; ++c) {
          const int id = (int)(u >> (c*4)) & 7;
          const float4 t = *(const float4*)&lut[((c*7 + id) << 6) + (l << 2)];
          e.x += t.x; e.y += t.y; e.z += t.z; e.w += t.w;
        }
      }
      float na2 = e.x*e.x + e.y*e.y + e.z*e.z + e.w*e.w;
      na2 = red16(na2);
      const int bsel = isUser ? 1 : 0;
      *(float4*)&s_dyn[O_CENT + bsel*512 + k*64 + l*4] = e;
      if (l == 0) s_dyn[O_CRN + bsel*8 + k] = RSQF(fmaxf(na2, 1e-12f));

      if (gg < 2) {  // gg0: ori_user (user lut); gg1: url_embed (url lut)
        const float* lutm = (gg == 0) ? s_ulut : s_llut;
        const int Fm  = (gg == 0) ? 7 : 5;
        const int ibm = (gg == 0) ? 0 : 7;
        float4 em = make_float4(0.f,0.f,0.f,0.f);
        for (int c = 0; c < Fm; ++c) {
          const int id = s_cidx[ibm + c];
          const float4 t = *(const float4*)&lutm[((c*7 + id) << 6) + (l << 2)];
          em.x += t.x; em.y += t.y; em.z += t.z; em.w += t.w;
        }
        if (gg == 0) {
          float nn = em.x*em.x + em.y*em.y + em.z*em.z + em.w*em.w;
          nn = red16(nn);
          *(float4*)&s_dyn[O_ORI + l*4] = em;
          if (l == 0) s_dyn[O_ORN] = RSQF(fmaxf(nn, 1e-12f));
        } else {
          *(float4*)&s_dyn[O_URLEMB + l*4] = em;
        }
      }
    }
    __syncthreads();

    // ---------- stage 3: hop-2 attention, one job per wave, atomic pair-combine ----------
    {
      const float* wb = &s_dyn[O_W + jb*64];
      for (int k1 = 0; k1 < 8; ++k1) {
        const float4 c4 = *(const float4*)&s_dyn[O_CENT + b3*512 + k1*64 + l*4];
        const float rnb = s_dyn[O_CRN + b3*8 + k1];
        float4 ek0, ek1; float cs0, cs1;
        #pragma unroll
        for (int p = 0; p < 2; ++p) {
          const int node = k1*8 + p*4 + g;
          const int nb = nibbase + node*F3;
          const int wq = nb >> 3;
          unsigned long long u =
              ((unsigned long long)(unsigned)s_pidx[wq + 1] << 32) | (unsigned)s_pidx[wq];
          u >>= ((nb & 7) << 2);
          float4 e = make_float4(0.f,0.f,0.f,0.f);
          if (F7) {
            #pragma unroll
            for (int c = 0; c < 7; ++c) {
              const int id = (int)(u >> (c*4)) & 7;
              const float4 t = *(const float4*)&lut3[((c*7 + id) << 6) + (l << 2)];
              e.x += t.x; e.y += t.y; e.z += t.z; e.w += t.w;
            }
          } else {
            #pragma unroll
            for (int c = 0; c < 5; ++c) {
              const int id = (int)(u >> (c*4)) & 7;
              const float4 t = *(const float4*)&lut3[((c*7 + id) << 6) + (l << 2)];
              e.x += t.x; e.y += t.y; e.z += t.z; e.w += t.w;
            }
          }
          float dot = e.x*c4.x + e.y*c4.y + e.z*c4.z + e.w*c4.w;
          float na2 = e.x*e.x + e.y*e.y + e.z*e.z + e.w*e.w;
          dot = red16(dot);
          na2 = red16(na2);
          const float cs = dot * RSQF(fmaxf(na2, 1e-12f)) * rnb;
          if (p == 0) { ek0 = e; cs0 = cs; } else { ek1 = e; cs1 = cs; }
        }
        // softmax over 8 cosines: |cs|<=1 so no max-subtract needed
        const float ex0 = __expf(cs0), ex1 = __expf(cs1);
        float ss = ex0 + ex1;
        ss += sx(ss, 16); ss += sx(ss, 32);
        const float w0 = wb[k1*8 + g], w1 = wb[k1*8 + 4 + g];
        float ax = fmaxf(ek0.x*w0, 0.f)*ex0 + fmaxf(ek1.x*w1, 0.f)*ex1;
        float ay = fmaxf(ek0.y*w0, 0.f)*ex0 + fmaxf(ek1.y*w1, 0.f)*ex1;
        float az = fmaxf(ek0.z*w0, 0.f)*ex0 + fmaxf(ek1.z*w1, 0.f)*ex1;
        float aw = fmaxf(ek0.w*w0, 0.f)*ex0 + fmaxf(ek1.w*w1, 0.f)*ex1;
        ax += sx(ax,16); ay += sx(ay,16); az += sx(az,16); aw += sx(aw,16);
        ax += sx(ax,32); ay += sx(ay,32); az += sx(az,32); aw += sx(aw,32);
        if (g == 0) {
          const float sc = 0.5f * RCPF(ss);   // 0.5 = (A+B)/2 pre-folded
          float* jp = &s_dyn[O_JOB + b3*512 + k1*64 + l*4];
          atomicAdd(jp + 0, ax*sc);
          atomicAdd(jp + 1, ay*sc);
          atomicAdd(jp + 2, az*sc);
          atomicAdd(jp + 3, aw*sc);
        }
      }
    }
    __syncthreads();

    // ---------- stage 4: W2 linear, j-split, atomic accumulate into b2-preinit H1 ----------
    for (int rr = 0; rr < 16; ++rr) {
      const int branch = rr >> 3, k = rr & 7;
      const float* xp = (wv < 2)
          ? &s_dyn[O_CENT + branch*512 + k*64 + wv*32]
          : &s_dyn[O_JOB  + branch*512 + k*64 + (wv - 2)*32];
      float a = 0.f;
      #pragma unroll
      for (int j4 = 0; j4 < 8; ++j4) {
        const float4 xv = *(const float4*)&xp[j4*4];   // lane-uniform broadcast
        a += xv.x*w2r[j4*4+0] + xv.y*w2r[j4*4+1] + xv.z*w2r[j4*4+2] + xv.w*w2r[j4*4+3];
      }
      atomicAdd(&s_h1[rr*64 + lane], a);
    }
    __syncthreads();
    {  // relu pass
      float4* hp = (float4*)&s_h1[tid*4];
      float4 v = *hp;
      v.x = fmaxf(v.x, 0.f); v.y = fmaxf(v.y, 0.f);
      v.z = fmaxf(v.z, 0.f); v.w = fmaxf(v.w, 0.f);
      *hp = v;
    }
    __syncthreads();

    // ---------- stage 5: hop-1 attention (waves 0,1) ----------
    if (wv < 2) {
      const float4 c4 = *(const float4*)&s_dyn[O_ORI + l*4];
      const float rno = s_dyn[O_ORN];
      const float* h1b = &s_h1[wv*512];
      const int wofs = (wv == 0) ? 8 : 0;   // url branch uses u1l weights
      float4 ek0, ek1; float cs0, cs1;
      #pragma unroll
      for (int p = 0; p < 2; ++p) {
        const int k = p*4 + g;
        const float4 e = *(const float4*)&h1b[k*64 + l*4];
        float dot = e.x*c4.x + e.y*c4.y + e.z*c4.z + e.w*c4.w;
        float na2 = e.x*e.x + e.y*e.y + e.z*e.z + e.w*e.w;
        dot = red16(dot);
        na2 = red16(na2);
        const float cs = dot * RSQF(fmaxf(na2, 1e-12f)) * rno;
        if (p == 0) { ek0 = e; cs0 = cs; } else { ek1 = e; cs1 = cs; }
      }
      const float ex0 = __expf(cs0), ex1 = __expf(cs1);
      float ss = ex0 + ex1;
      ss += sx(ss, 16); ss += sx(ss, 32);
      const float w0 = s_dyn[O_W1H + wofs + g], w1 = s_dyn[O_W1H + wofs + 4 + g];
      float ax = fmaxf(ek0.x*w0, 0.f)*ex0 + fmaxf(ek1.x*w1, 0.f)*ex1;
      float ay = fmaxf(ek0.y*w0, 0.f)*ex0 + fmaxf(ek1.y*w1, 0.f)*ex1;
      float az = fmaxf(ek0.z*w0, 0.f)*ex0 + fmaxf(ek1.z*w1, 0.f)*ex1;
      float aw = fmaxf(ek0.w*w0, 0.f)*ex0 + fmaxf(ek1.w*w1, 0.f)*ex1;
      ax += sx(ax,16); ay += sx(ay,16); az += sx(az,16); aw += sx(aw,16);
      ax += sx(ax,32); ay += sx(ay,32); az += sx(az,32); aw += sx(aw,32);
      if (g == 0) {
        const float sc = 0.5f * RCPF(ss);
        *(float4*)&s_dyn[O_GA1 + wv*64 + l*4] =
            make_float4(ax*sc, ay*sc, az*sc, aw*sc);
      }
    }
    __syncthreads();

    // ---------- stage 6: W1 linear partials ----------
    {
      float a = 0.f;
      if (wv < 2) {
        const float* xp = &s_dyn[O_ORI + wv*32];
        #pragma unroll
        for (int j4 = 0; j4 < 8; ++j4) {
          const float4 xv = *(const float4*)&xp[j4*4];
          a += xv.x*w1r[j4*4+0] + xv.y*w1r[j4*4+1] + xv.z*w1r[j4*4+2] + xv.w*w1r[j4*4+3];
        }
      } else {
        const float* xa = &s_dyn[O_GA1 + (wv - 2)*32];
        const float* xb = &s_dyn[O_GA1 + 64 + (wv - 2)*32];
        #pragma unroll
        for (int j4 = 0; j4 < 8; ++j4) {
          const float4 va = *(const float4*)&xa[j4*4];
          const float4 vb = *(const float4*)&xb[j4*4];
          a += (va.x+vb.x)*w1r[j4*4+0] + (va.y+vb.y)*w1r[j4*4+1]
             + (va.z+vb.z)*w1r[j4*4+2] + (va.w+vb.w)*w1r[j4*4+3];
        }
      }
      s_dyn[O_PART + wv*64 + lane] = a;
    }
    __syncthreads();

    // ---------- stage 7: relu(W1) -> Wo -> softmax(2) ----------
    if (wv == 0) {
      float ue = b1v;
      #pragma unroll
      for (int q = 0; q < 4; ++q) ue += s_dyn[O_PART + q*64 + lane];
      ue = fmaxf(ue, 0.f);
      const float ul = s_dyn[O_URLEMB + lane];
      float p0 = ue*wo0 + ul*wo1;
      float p1 = ue*wo2 + ul*wo3;
      p0 = red16(p0); p0 += sx(p0, 16); p0 += sx(p0, 32);
      p1 = red16(p1); p1 += sx(p1, 16); p1 += sx(p1, 32);
      if (lane == 0) {
        const float l0 = p0 + bo0, l1 = p1 + bo1;
        const float mx = fmaxf(l0, l1);
        const float q0 = __expf(l0 - mx), q1 = __expf(l1 - mx);
        const float rinv = RCPF(q0 + q1);
        g_out[n*2 + 0] = q0 * rinv;
        g_out[n*2 + 1] = q1 * rinv;
      }
    }
  }
}

extern "C" void kernel_launch(void* const* d_in, const int* in_sizes, int n_in,
                              void* d_out, int out_size, void* d_ws, size_t ws_size,
                              hipStream_t stream) {
  (void)in_sizes; (void)n_in; (void)d_ws; (void)ws_size; (void)out_size;
  const int*   g_user_f = (const int*)d_in[1];
  const int*   g_url_f  = (const int*)d_in[2];
  const int*   g_u1u_f  = (const int*)d_in[3];
  const float* g_u1u_w  = (const float*)d_in[4];
  const int*   g_u1l_f  = (const int*)d_in[5];
  const float* g_u1l_w  = (const float*)d_in[6];
  const int*   g_u2u_f  = (const int*)d_in[7];
  const float* g_u2u_w  = (const float*)d_in[8];
  const int*   g_u2l_f  = (const int*)d_in[9];
  const float* g_u2l_w  = (const float*)d_in[10];
  const int*   g_l2u_f  = (const int*)d_in[11];
  const float* g_l2u_w  = (const float*)d_in[12];
  const int*   g_l2l_f  = (const int*)d_in[13];
  const float* g_l2l_w  = (const float*)d_in[14];
  const float* g_utab   = (const float*)d_in[15];
  const float* g_ltab   = (const float*)d_in[16];
  const float* g_W2     = (const float*)d_in[17];
  const float* g_b2     = (const float*)d_in[18];
  const float* g_W1     = (const float*)d_in[19];
  const float* g_b1     = (const float*)d_in[20];
  const float* g_Wo     = (const float*)d_in[21];
  const float* g_bo     = (const float*)d_in[22];

  gcn_fused<<<NSAMP / SPB, TPB, 0, stream>>>(
      g_user_f, g_url_f, g_u1u_f, g_u1u_w, g_u1l_f, g_u1l_w,
      g_u2u_f, g_u2u_w, g_u2l_f, g_u2l_w, g_l2u_f, g_l2u_w, g_l2l_f, g_l2l_w,
      g_utab, g_ltab, g_W2, g_b2, g_W1, g_b1, g_Wo, g_bo,
      (float*)d_out);
}

// Round 4
// 531.056 us; speedup vs baseline: 1.0387x; 1.0387x over previous
//
#include <hip/hip_runtime.h>

#define TPB 256
#define SPB 4
#define NSAMP 8192

#if __has_builtin(__builtin_amdgcn_rcpf)
#define RCPF(x) __builtin_amdgcn_rcpf(x)
#else
#define RCPF(x) (1.0f/(x))
#endif
#if __has_builtin(__builtin_amdgcn_rsqf)
#define RSQF(x) __builtin_amdgcn_rsqf(x)
#else
#define RSQF(x) rsqrtf(x)
#endif

// ---- s_dyn float offsets ----
#define O_CENT   0      // [2][8][64] hop-1 centers (url=0,user=1)
#define O_CRN    1024   // [16] reciprocal clamped norms
#define O_ORI    1040   // [64] ori_user
#define O_ORN    1104   // [1]  (+3 pad)
#define O_URLEMB 1108   // [64]
#define O_JOB    1172   // [2][8][64] combined hop-2 outputs (atomic accum)
#define O_H1     2196   // [2][8][64] relu(W2 linear) (atomic accum, b2-preinit)
#define O_PIDX   3220   // [208] ints: 4-bit packed ids
#define O_W      3428   // [256] hop-2 weights (l2u,l2l,u2u,u2l)
#define O_GA1    3684   // [2][64] hop-1 attention outputs
#define O_PART   3812   // [4][64] W1 partials
#define O_W1H    4068   // [16] hop-1 weights (u1u 0..7, u1l 8..15)
#define O_CIDX   4084   // [12] ints (user 7, url 5)
#define DYN_SZ   4096

__device__ __forceinline__ float sx(float v, int m) { return __shfl_xor(v, m, 64); }

// 16-lane sum reduce entirely in the VALU pipe via DPP (ctrl must be constexpr).
template <int CTRL>
__device__ __forceinline__ float dpp_add(float v) {
  return v + __int_as_float(__builtin_amdgcn_update_dpp(
      0, __float_as_int(v), CTRL, 0xf, 0xf, true));
}
__device__ __forceinline__ float red16(float v) {
  v = dpp_add<0xB1>(v);   // quad_perm(1,0,3,2)  = xor1
  v = dpp_add<0x4E>(v);   // quad_perm(2,3,0,1)  = xor2
  v = dpp_add<0x141>(v);  // row_half_mirror
  v = dpp_add<0x140>(v);  // row_mirror
  return v;
}

__global__ __launch_bounds__(TPB, 4)
void gcn_fused(const int* __restrict__ g_user_f, const int* __restrict__ g_url_f,
               const int* __restrict__ g_u1u_f, const float* __restrict__ g_u1u_w,
               const int* __restrict__ g_u1l_f, const float* __restrict__ g_u1l_w,
               const int* __restrict__ g_u2u_f, const float* __restrict__ g_u2u_w,
               const int* __restrict__ g_u2l_f, const float* __restrict__ g_u2l_w,
               const int* __restrict__ g_l2u_f, const float* __restrict__ g_l2u_w,
               const int* __restrict__ g_l2l_f, const float* __restrict__ g_l2l_w,
               const float* __restrict__ g_utab, const float* __restrict__ g_ltab,
               const float* __restrict__ g_W2, const float* __restrict__ g_b2,
               const float* __restrict__ g_W1, const float* __restrict__ g_b1,
               const float* __restrict__ g_Wo, const float* __restrict__ g_bo,
               float* __restrict__ g_out)
{
  __shared__ __align__(16) float s_lut[5376];  // user rows [0,3136), url rows [3136,5376), stride 64
  __shared__ __align__(16) float s_dyn[DYN_SZ];

  const int tid  = threadIdx.x;
  const int wv   = tid >> 6;        // wave 0..3
  const int lane = tid & 63;
  const int g    = (tid >> 4) & 3;  // 16-lane group in wave
  const int l    = tid & 15;        // owns dims l*4..l*4+3

  float* s_ulut = s_lut;
  float* s_llut = s_lut + 49*64;
  int*   s_pidx = (int*)&s_dyn[O_PIDX];
  int*   s_cidx = (int*)&s_dyn[O_CIDX];
  float* s_h1   = &s_dyn[O_H1];

  // ---------- once per block: W2^T columns into registers (s_lut as scratch) ----------
  // thread (wv,lane) holds w2r[jj] = W2[lane][wv*32+jj]. W1 is NOT register-cached
  // (stage 6 is 1/16 the MACs of stage 4) — keeps persistent regs < the 128 cap, no spill.
  float w2r[32];
  for (int half = 0; half < 2; ++half) {
    for (int i = tid; i < 4096; i += TPB) {
      const int r = i >> 7, j = i & 127;
      s_lut[r*132 + j] = g_W2[(half*32 + r)*128 + j];
    }
    __syncthreads();
    if ((lane >> 5) == half) {
      const int lr = lane & 31;
      #pragma unroll
      for (int jj = 0; jj < 32; ++jj)
        w2r[jj] = s_lut[lr*132 + wv*32 + jj];
    }
    __syncthreads();
  }

  // ---------- once per block: stage embedding LUTs (49+35 live rows only) ----------
  {
    constexpr int uoff[7] = {0,11577,11588,11599,11610,11621,11642};
    #pragma unroll
    for (int c = 0; c < 7; ++c)
      for (int i = tid; i < 448; i += TPB)
        s_ulut[c*448 + i] = g_utab[(uoff[c] + (i >> 6))*64 + (i & 63)];
    constexpr int loff[5] = {0,4733,4754,4761,4772};
    #pragma unroll
    for (int c = 0; c < 5; ++c)
      for (int i = tid; i < 448; i += TPB)
        s_llut[c*448 + i] = g_ltab[(loff[c] + (i >> 6))*64 + (i & 63)];
  }

  const float b2v = g_b2[lane];

  // per-wave hop-2 job: jb0=url_2_user, jb1=url_2_url, jb2=user_2_user, jb3=user_2_url
  const int  jb      = wv;
  const bool F7      = (jb == 0 || jb == 2);
  const int  F3      = F7 ? 7 : 5;
  const float* lut3  = F7 ? s_ulut : s_llut;
  const int  nibbase = (jb == 0) ? 768 : (jb == 1) ? 1216 : (jb == 2) ? 0 : 448;
  const int  b3      = jb >> 1;   // 0=url-branch centers, 1=user-branch

  #pragma unroll 1
  for (int s = 0; s < SPB; ++s) {
    const int n = blockIdx.x * SPB + s;
    __syncthreads();   // prev-sample readers done before restaging

    // ---------- stage 1: pack ids (4-bit), stage weights, init JOB/H1 ----------
    if (tid < 192) {           // hop-2: 1536 ids -> 192 words [u2u,u2l,l2u,l2l]
      const int w = tid;
      const int* ptr; int rel;
      if (w < 56)       { ptr = g_u2u_f + n*448; rel = w; }
      else if (w < 96)  { ptr = g_u2l_f + n*320; rel = w - 56; }
      else if (w < 152) { ptr = g_l2u_f + n*448; rel = w - 96; }
      else              { ptr = g_l2l_f + n*320; rel = w - 152; }
      const int4 a = *(const int4*)(ptr + rel*8);
      const int4 b = *(const int4*)(ptr + rel*8 + 4);
      s_pidx[w] = (a.x&7) | ((a.y&7)<<4) | ((a.z&7)<<8) | ((a.w&7)<<12)
                | ((b.x&7)<<16) | ((b.y&7)<<20) | ((b.z&7)<<24) | ((b.w&7)<<28);
    } else if (tid < 204) {    // u1u (7 words) + u1l (5 words)
      const int w = tid - 192;
      const int* ptr; int rel;
      if (w < 7) { ptr = g_u1u_f + n*56; rel = w; } else { ptr = g_u1l_f + n*40; rel = w - 7; }
      const int4 a = *(const int4*)(ptr + rel*8);
      const int4 b = *(const int4*)(ptr + rel*8 + 4);
      s_pidx[192 + w] = (a.x&7) | ((a.y&7)<<4) | ((a.z&7)<<8) | ((a.w&7)<<12)
                      | ((b.x&7)<<16) | ((b.y&7)<<20) | ((b.z&7)<<24) | ((b.w&7)<<28);
    } else if (tid < 216) {    // center ids, unpacked
      const int t = tid - 204;
      s_cidx[t] = (t < 7) ? g_user_f[n*7 + t] : g_url_f[n*5 + (t - 7)];
    } else if (tid < 232) {    // hop-1 weights
      const int t = tid - 216;
      s_dyn[O_W1H + t] = (t < 8) ? g_u1u_w[n*8 + t] : g_u1l_w[n*8 + (t - 8)];
    }
    if (tid < 64) {            // hop-2 weights, float4
      const float* wp = (tid < 16) ? g_l2u_w : (tid < 32) ? g_l2l_w
                       : (tid < 48) ? g_u2u_w : g_u2l_w;
      *(float4*)&s_dyn[O_W + (tid >> 4)*64 + (tid & 15)*4] =
          *(const float4*)&wp[n*64 + (tid & 15)*4];
    }
    *(float4*)&s_dyn[O_JOB + tid*4] = make_float4(0.f, 0.f, 0.f, 0.f);
    #pragma unroll
    for (int r = 0; r < 4; ++r) s_h1[(wv*4 + r)*64 + lane] = b2v;   // b2 pre-init
    __syncthreads();

    // ---------- stage 2: hop-1 centers + ori_user + url_embed ----------
    {
      const int gg = tid >> 4;          // 0..7 url centers, 8..15 user centers (wave-uniform F)
      const bool isUser = gg >= 8;
      const int k = gg & 7;
      const float* lut = isUser ? s_ulut : s_llut;
      const int nb = isUser ? (1536 + k*7) : (1592 + k*5);
      const int wq = nb >> 3;
      unsigned long long u =
          ((unsigned long long)(unsigned)s_pidx[wq + 1] << 32) | (unsigned)s_pidx[wq];
      u >>= ((nb & 7) << 2);
      float4 e = make_float4(0.f,0.f,0.f,0.f);
      if (isUser) {
        #pragma unroll
        for (int c = 0; c < 7; ++c) {
          const int id = (int)(u >> (c*4)) & 7;
          const float4 t = *(const float4*)&lut[((c*7 + id) << 6) + (l << 2)];
          e.x += t.x; e.y += t.y; e.z += t.z; e.w += t.w;
        }
      } else {
        #pragma unroll
        for (int c = 0; c < 5; ++c) {
          const int id = (int)(u >> (c*4)) & 7;
          const float4 t = *(const float4*)&lut[((c*7 + id) << 6) + (l << 2)];
          e.x += t.x; e.y += t.y; e.z += t.z; e.w += t.w;
        }
      }
      float na2 = e.x*e.x + e.y*e.y + e.z*e.z + e.w*e.w;
      na2 = red16(na2);
      const int bsel = isUser ? 1 : 0;
      *(float4*)&s_dyn[O_CENT + bsel*512 + k*64 + l*4] = e;
      if (l == 0) s_dyn[O_CRN + bsel*8 + k] = RSQF(fmaxf(na2, 1e-12f));

      if (gg < 2) {  // gg0: ori_user (user lut); gg1: url_embed (url lut)
        const float* lutm = (gg == 0) ? s_ulut : s_llut;
        const int Fm  = (gg == 0) ? 7 : 5;
        const int ibm = (gg == 0) ? 0 : 7;
        float4 em = make_float4(0.f,0.f,0.f,0.f);
        for (int c = 0; c < Fm; ++c) {
          const int id = s_cidx[ibm + c];
          const float4 t = *(const float4*)&lutm[((c*7 + id) << 6) + (l << 2)];
          em.x += t.x; em.y += t.y; em.z += t.z; em.w += t.w;
        }
        if (gg == 0) {
          float nn = em.x*em.x + em.y*em.y + em.z*em.z + em.w*em.w;
          nn = red16(nn);
          *(float4*)&s_dyn[O_ORI + l*4] = em;
          if (l == 0) s_dyn[O_ORN] = RSQF(fmaxf(nn, 1e-12f));
        } else {
          *(float4*)&s_dyn[O_URLEMB + l*4] = em;
        }
      }
    }
    __syncthreads();

    // ---------- stage 3: hop-2 attention, one job per wave, atomic pair-combine ----------
    {
      const float* wb = &s_dyn[O_W + jb*64];
      for (int k1 = 0; k1 < 8; ++k1) {
        const float4 c4 = *(const float4*)&s_dyn[O_CENT + b3*512 + k1*64 + l*4];
        const float rnb = s_dyn[O_CRN + b3*8 + k1];
        float4 ek0, ek1; float cs0, cs1;
        #pragma unroll
        for (int p = 0; p < 2; ++p) {
          const int node = k1*8 + p*4 + g;
          const int nb = nibbase + node*F3;
          const int wq = nb >> 3;
          unsigned long long u =
              ((unsigned long long)(unsigned)s_pidx[wq + 1] << 32) | (unsigned)s_pidx[wq];
          u >>= ((nb & 7) << 2);
          float4 e = make_float4(0.f,0.f,0.f,0.f);
          if (F7) {
            #pragma unroll
            for (int c = 0; c < 7; ++c) {
              const int id = (int)(u >> (c*4)) & 7;
              const float4 t = *(const float4*)&lut3[((c*7 + id) << 6) + (l << 2)];
              e.x += t.x; e.y += t.y; e.z += t.z; e.w += t.w;
            }
          } else {
            #pragma unroll
            for (int c = 0; c < 5; ++c) {
              const int id = (int)(u >> (c*4)) & 7;
              const float4 t = *(const float4*)&lut3[((c*7 + id) << 6) + (l << 2)];
              e.x += t.x; e.y += t.y; e.z += t.z; e.w += t.w;
            }
          }
          float dot = e.x*c4.x + e.y*c4.y + e.z*c4.z + e.w*c4.w;
          float na2 = e.x*e.x + e.y*e.y + e.z*e.z + e.w*e.w;
          dot = red16(dot);
          na2 = red16(na2);
          const float cs = dot * RSQF(fmaxf(na2, 1e-12f)) * rnb;
          if (p == 0) { ek0 = e; cs0 = cs; } else { ek1 = e; cs1 = cs; }
        }
        // softmax over 8 cosines: |cs|<=1 so no max-subtract needed
        const float ex0 = __expf(cs0), ex1 = __expf(cs1);
        float ss = ex0 + ex1;
        ss += sx(ss, 16); ss += sx(ss, 32);
        const float w0 = wb[k1*8 + g], w1 = wb[k1*8 + 4 + g];
        float ax = fmaxf(ek0.x*w0, 0.f)*ex0 + fmaxf(ek1.x*w1, 0.f)*ex1;
        float ay = fmaxf(ek0.y*w0, 0.f)*ex0 + fmaxf(ek1.y*w1, 0.f)*ex1;
        float az = fmaxf(ek0.z*w0, 0.f)*ex0 + fmaxf(ek1.z*w1, 0.f)*ex1;
        float aw = fmaxf(ek0.w*w0, 0.f)*ex0 + fmaxf(ek1.w*w1, 0.f)*ex1;
        ax += sx(ax,16); ay += sx(ay,16); az += sx(az,16); aw += sx(aw,16);
        ax += sx(ax,32); ay += sx(ay,32); az += sx(az,32); aw += sx(aw,32);
        if (g == 0) {
          const float sc = 0.5f * RCPF(ss);   // 0.5 = (A+B)/2 pre-folded
          float* jp = &s_dyn[O_JOB + b3*512 + k1*64 + l*4];
          atomicAdd(jp + 0, ax*sc);
          atomicAdd(jp + 1, ay*sc);
          atomicAdd(jp + 2, az*sc);
          atomicAdd(jp + 3, aw*sc);
        }
      }
    }
    __syncthreads();

    // ---------- stage 4: W2 linear, j-split, atomic accumulate into b2-preinit H1 ----------
    for (int rr = 0; rr < 16; ++rr) {
      const int branch = rr >> 3, k = rr & 7;
      const float* xp = (wv < 2)
          ? &s_dyn[O_CENT + branch*512 + k*64 + wv*32]
          : &s_dyn[O_JOB  + branch*512 + k*64 + (wv - 2)*32];
      float a = 0.f;
      #pragma unroll
      for (int j4 = 0; j4 < 8; ++j4) {
        const float4 xv = *(const float4*)&xp[j4*4];   // lane-uniform broadcast
        a += xv.x*w2r[j4*4+0] + xv.y*w2r[j4*4+1] + xv.z*w2r[j4*4+2] + xv.w*w2r[j4*4+3];
      }
      atomicAdd(&s_h1[rr*64 + lane], a);
    }
    __syncthreads();
    {  // relu pass
      float4* hp = (float4*)&s_h1[tid*4];
      float4 v = *hp;
      v.x = fmaxf(v.x, 0.f); v.y = fmaxf(v.y, 0.f);
      v.z = fmaxf(v.z, 0.f); v.w = fmaxf(v.w, 0.f);
      *hp = v;
    }
    __syncthreads();

    // ---------- stage 5: hop-1 attention (waves 0,1) ----------
    if (wv < 2) {
      const float4 c4 = *(const float4*)&s_dyn[O_ORI + l*4];
      const float rno = s_dyn[O_ORN];
      const float* h1b = &s_h1[wv*512];
      const int wofs = (wv == 0) ? 8 : 0;   // url branch uses u1l weights
      float4 ek0, ek1; float cs0, cs1;
      #pragma unroll
      for (int p = 0; p < 2; ++p) {
        const int k = p*4 + g;
        const float4 e = *(const float4*)&h1b[k*64 + l*4];
        float dot = e.x*c4.x + e.y*c4.y + e.z*c4.z + e.w*c4.w;
        float na2 = e.x*e.x + e.y*e.y + e.z*e.z + e.w*e.w;
        dot = red16(dot);
        na2 = red16(na2);
        const float cs = dot * RSQF(fmaxf(na2, 1e-12f)) * rno;
        if (p == 0) { ek0 = e; cs0 = cs; } else { ek1 = e; cs1 = cs; }
      }
      const float ex0 = __expf(cs0), ex1 = __expf(cs1);
      float ss = ex0 + ex1;
      ss += sx(ss, 16); ss += sx(ss, 32);
      const float w0 = s_dyn[O_W1H + wofs + g], w1 = s_dyn[O_W1H + wofs + 4 + g];
      float ax = fmaxf(ek0.x*w0, 0.f)*ex0 + fmaxf(ek1.x*w1, 0.f)*ex1;
      float ay = fmaxf(ek0.y*w0, 0.f)*ex0 + fmaxf(ek1.y*w1, 0.f)*ex1;
      float az = fmaxf(ek0.z*w0, 0.f)*ex0 + fmaxf(ek1.z*w1, 0.f)*ex1;
      float aw = fmaxf(ek0.w*w0, 0.f)*ex0 + fmaxf(ek1.w*w1, 0.f)*ex1;
      ax += sx(ax,16); ay += sx(ay,16); az += sx(az,16); aw += sx(aw,16);
      ax += sx(ax,32); ay += sx(ay,32); az += sx(az,32); aw += sx(aw,32);
      if (g == 0) {
        const float sc = 0.5f * RCPF(ss);
        *(float4*)&s_dyn[O_GA1 + wv*64 + l*4] =
            make_float4(ax*sc, ay*sc, az*sc, aw*sc);
      }
    }
    __syncthreads();

    // ---------- stage 6: W1 linear partials (W1 read from global; L1/L2-hot) ----------
    {
      const float* w1p = g_W1 + lane*128 + wv*32;   // W1[lane][wv*32 + jj]
      float a = 0.f;
      if (wv < 2) {
        const float* xp = &s_dyn[O_ORI + wv*32];
        #pragma unroll
        for (int j4 = 0; j4 < 8; ++j4) {
          const float4 xv = *(const float4*)&xp[j4*4];
          const float4 wq = *(const float4*)&w1p[j4*4];
          a += xv.x*wq.x + xv.y*wq.y + xv.z*wq.z + xv.w*wq.w;
        }
      } else {
        const float* xa = &s_dyn[O_GA1 + (wv - 2)*32];
        const float* xb = &s_dyn[O_GA1 + 64 + (wv - 2)*32];
        #pragma unroll
        for (int j4 = 0; j4 < 8; ++j4) {
          const float4 va = *(const float4*)&xa[j4*4];
          const float4 vb = *(const float4*)&xb[j4*4];
          const float4 wq = *(const float4*)&w1p[j4*4];
          a += (va.x+vb.x)*wq.x + (va.y+vb.y)*wq.y
             + (va.z+vb.z)*wq.z + (va.w+vb.w)*wq.w;
        }
      }
      s_dyn[O_PART + wv*64 + lane] = a;
    }
    __syncthreads();

    // ---------- stage 7: relu(W1) -> Wo -> softmax(2) ----------
    if (wv == 0) {
      float ue = g_b1[lane];
      #pragma unroll
      for (int q = 0; q < 4; ++q) ue += s_dyn[O_PART + q*64 + lane];
      ue = fmaxf(ue, 0.f);
      const float ul = s_dyn[O_URLEMB + lane];
      float p0 = ue*g_Wo[lane]     + ul*g_Wo[64 + lane];
      float p1 = ue*g_Wo[128+lane] + ul*g_Wo[192 + lane];
      p0 = red16(p0); p0 += sx(p0, 16); p0 += sx(p0, 32);
      p1 = red16(p1); p1 += sx(p1, 16); p1 += sx(p1, 32);
      if (lane == 0) {
        const float l0 = p0 + g_bo[0], l1 = p1 + g_bo[1];
        const float mx = fmaxf(l0, l1);
        const float q0 = __expf(l0 - mx), q1 = __expf(l1 - mx);
        const float rinv = RCPF(q0 + q1);
        g_out[n*2 + 0] = q0 * rinv;
        g_out[n*2 + 1] = q1 * rinv;
      }
    }
  }
}

extern "C" void kernel_launch(void* const* d_in, const int* in_sizes, int n_in,
                              void* d_out, int out_size, void* d_ws, size_t ws_size,
                              hipStream_t stream) {
  (void)in_sizes; (void)n_in; (void)d_ws; (void)ws_size; (void)out_size;
  const int*   g_user_f = (const int*)d_in[1];
  const int*   g_url_f  = (const int*)d_in[2];
  const int*   g_u1u_f  = (const int*)d_in[3];
  const float* g_u1u_w  = (const float*)d_in[4];
  const int*   g_u1l_f  = (const int*)d_in[5];
  const float* g_u1l_w  = (const float*)d_in[6];
  const int*   g_u2u_f  = (const int*)d_in[7];
  const float* g_u2u_w  = (const float*)d_in[8];
  const int*   g_u2l_f  = (const int*)d_in[9];
  const float* g_u2l_w  = (const float*)d_in[10];
  const int*   g_l2u_f  = (const int*)d_in[11];
  const float* g_l2u_w  = (const float*)d_in[12];
  const int*   g_l2l_f  = (const int*)d_in[13];
  const float* g_l2l_w  = (const float*)d_in[14];
  const float* g_utab   = (const float*)d_in[15];
  const float* g_ltab   = (const float*)d_in[16];
  const float* g_W2     = (const float*)d_in[17];
  const float* g_b2     = (const float*)d_in[18];
  const float* g_W1     = (const float*)d_in[19];
  const float* g_b1     = (const float*)d_in[20];
  const float* g_Wo     = (const float*)d_in[21];
  const float* g_bo     = (const float*)d_in[22];

  gcn_fused<<<NSAMP / SPB, TPB, 0, stream>>>(
      g_user_f, g_url_f, g_u1u_f, g_u1u_w, g_u1l_f, g_u1l_w,
      g_u2u_f, g_u2u_w, g_u2l_f, g_u2l_w, g_l2u_f, g_l2u_w, g_l2l_f, g_l2l_w,
      g_utab, g_ltab, g_W2, g_b2, g_W1, g_b1, g_Wo, g_bo,
      (float*)d_out);
}